// Round 19
// baseline (324.188 us; speedup 1.0000x reference)
//
#include <hip/hip_runtime.h>
#include <hip/hip_fp16.h>
#include <math.h>

#define N_NODES 100000
#define N_EDGES 1600000
#define IN_CH   64
#define GCN_CH  64
#define OUT_CH  32
#define MAXDEG  48   // P(deg >= 48) ~ 1e-10/node under Binomial(1.6M, 1e-5); guarded

#define EW_SCALE  32768.0f              // 15-bit fixed point for ELL records
#define EW_INV    (1.0f / 32768.0f)

// counting-sort geometry
#define BSHIFT   7
#define NBUCK    1024                         // col>>7  (col < 2^17)
#define NBUCK_USED ((N_NODES + 127) / 128)    // 782 buckets actually populated
#define EPB      4096                         // edges per hist/scatter block
#define NBLK     ((N_EDGES + EPB - 1) / EPB)  // 391
#define HIST_TOT (NBUCK * NBLK)               // 400384 = 391 chunks of 1024 exactly
#define NCHUNK   (HIST_TOT / 1024)            // 391 (exact)
#define GEMMB    ((N_NODES + 63) / 64)        // 1563 gemm blocks (64 rows @ 1024 thr)

// channel-chunked gather geometry: 8 chunks x 8 fp16 channels (16 B/row-chunk).
// chunk table = 1.6 MB -> per-XCD L2 resident (chunk = blockIdx % 8).
#define NCH        8
#define NPB        32                         // nodes per gather block (8 waves x 4)
#define GGATHER    (N_NODES / NPB * NCH)      // 3125 * 8 = 25000 (exact)
#define GOUT       (N_NODES / 32)             // 3125 (exact)

// ---------------------------------------------------------------------------
// 1) hist: per-block LDS histogram over 1024 coarse buckets.
// ---------------------------------------------------------------------------
__global__ void hist_kernel(const int* __restrict__ col, unsigned* __restrict__ hist_g) {
    __shared__ unsigned sh[NBUCK];
    int blk = blockIdx.x;
    for (int i = threadIdx.x; i < NBUCK; i += 1024) sh[i] = 0;
    __syncthreads();
    int base = blk * EPB;
    int lim  = min(EPB, N_EDGES - base);
    for (int i = threadIdx.x; i < lim; i += 1024)
        atomicAdd(&sh[(unsigned)col[base + i] >> BSHIFT], 1u);
    __syncthreads();
    for (int b = threadIdx.x; b < NBUCK; b += 1024)
        hist_g[(size_t)b * NBLK + blk] = sh[b];
}

// ---------------------------------------------------------------------------
// 2) scan1: per-chunk exclusive scan; blockSums keeps RAW chunk totals.
// ---------------------------------------------------------------------------
__global__ void scan1_kernel(const unsigned* __restrict__ in, unsigned* __restrict__ outp,
                             unsigned* __restrict__ blockSums) {
    __shared__ unsigned sdata[256];
    int t = threadIdx.x;
    int base = blockIdx.x * 1024 + t * 4;
    unsigned v[4];
    unsigned sum = 0;
#pragma unroll
    for (int i = 0; i < 4; ++i) { v[i] = in[base + i]; sum += v[i]; }
    sdata[t] = sum;
    __syncthreads();
    for (int off = 1; off < 256; off <<= 1) {
        unsigned x = (t >= off) ? sdata[t - off] : 0;
        __syncthreads();
        sdata[t] += x;
        __syncthreads();
    }
    unsigned excl = sdata[t] - sum;
    if (t == 255) blockSums[blockIdx.x] = sdata[t];
    unsigned run = excl;
#pragma unroll
    for (int i = 0; i < 4; ++i) { outp[base + i] = run; run += v[i]; }
}

// helper: inclusive Hillis-Steele scan of raw chunk totals into cb[512].
__device__ inline void chunk_scan(const unsigned* __restrict__ bsum, unsigned* cb,
                                  int t) {
    if (t < 512) cb[t] = (t < NCHUNK) ? bsum[t] : 0u;
    __syncthreads();
    for (int off = 1; off < 512; off <<= 1) {
        unsigned x = 0;
        if (t < 512 && t >= off) x = cb[t - off];
        __syncthreads();
        if (t < 512) cb[t] += x;
        __syncthreads();
    }
}

// ---------------------------------------------------------------------------
// 3) scatter (+ fused layer-1 GEMM, block-role split).
//    scatter role: block-local counting sort in LDS -> coalesced bucket-run
//    global writes.  gemm role: Yc[8][N][8] = fp16( X @ W1 ), chunk-major.
// ---------------------------------------------------------------------------
__global__ void scatter_gemm_kernel(const int* __restrict__ row, const int* __restrict__ col,
                                    const float* __restrict__ ew,
                                    const unsigned* __restrict__ scanned,
                                    const unsigned* __restrict__ blockSums,
                                    unsigned long long* __restrict__ srt,
                                    const float* __restrict__ X, const float* __restrict__ W,
                                    __half* __restrict__ Y) {
    __shared__ unsigned cb[512];
    __shared__ unsigned cur[NBUCK];
    __shared__ unsigned lbase[NBUCK];
    __shared__ unsigned lcur[NBUCK];
    __shared__ unsigned wsum[16];
    __shared__ unsigned long long lrec[EPB];     // 32 KB
    __shared__ float4   Ws[64][16];
    int t = threadIdx.x;
    int bid = blockIdx.x;

    if (bid < NBLK) {
        // ---- scatter role ----
        chunk_scan(blockSums, cb, t);
        lcur[t] = 0;
        __syncthreads();

        int blk  = bid;
        int base = blk * EPB;
        int lim  = min(EPB, N_EDGES - base);

        unsigned long long recs[4];
        unsigned bks[4];
#pragma unroll
        for (int k = 0; k < 4; ++k) {
            int i = t + k * 1024;
            bool ok = i < lim;
            int e = base + (ok ? i : 0);
            unsigned c = (unsigned)col[e];
            unsigned r = (unsigned)row[e];
            float    w = ew[e];
            unsigned u15 = min((unsigned)(w * EW_SCALE + 0.5f), 32767u);
            recs[k] = ((unsigned long long)c << 32) | ((r << 15) | u15);
            bks[k]  = c >> BSHIFT;
            if (ok) atomicAdd(&lcur[bks[k]], 1u);
        }
        __syncthreads();

        {
            unsigned v = lcur[t];
            unsigned inc = v;
#pragma unroll
            for (int off = 1; off < 64; off <<= 1) {
                unsigned u = __shfl_up(inc, off, 64);
                if ((t & 63) >= off) inc += u;
            }
            if ((t & 63) == 63) wsum[t >> 6] = inc;
            __syncthreads();
            unsigned wprefix = 0;
            int wid = t >> 6;
            for (int wv = 0; wv < wid; ++wv) wprefix += wsum[wv];
            lbase[t] = wprefix + inc - v;
            size_t hidx = (size_t)t * NBLK + blk;
            unsigned chunk = (unsigned)(hidx >> 10);
            cur[t]  = scanned[hidx] + (chunk ? cb[chunk - 1] : 0u);
            lcur[t] = lbase[t];
        }
        __syncthreads();

#pragma unroll
        for (int k = 0; k < 4; ++k) {
            int i = t + k * 1024;
            if (i < lim) {
                unsigned p = atomicAdd(&lcur[bks[k]], 1u);
                lrec[p] = recs[k];
            }
        }
        __syncthreads();

        for (int j = t; j < lim; j += 1024) {
            unsigned long long v = lrec[j];
            unsigned b = (unsigned)(v >> 32) >> BSHIFT;
            unsigned gpos = cur[b] + ((unsigned)j - lbase[b]);
            srt[gpos] = v;
        }
    } else {
        // ---- gemm role: 1024 threads, 64 rows/block, chunk-major store ----
        ((float4*)Ws)[t] = ((const float4*)W)[t];
        __syncthreads();
        int gb  = bid - NBLK;
        int q   = t & 15;
        int sub = t >> 4;
        int rw  = gb * 64 + sub;
        if (rw >= N_NODES) return;
        const float4* xr = (const float4*)(X + (size_t)rw * 64);
        float4 acc = {0.f, 0.f, 0.f, 0.f};
#pragma unroll
        for (int k4 = 0; k4 < 16; ++k4) {
            float4 xv = xr[k4];
#pragma unroll
            for (int j = 0; j < 4; ++j) {
                float xs = (j == 0) ? xv.x : (j == 1) ? xv.y : (j == 2) ? xv.z : xv.w;
                float4 wv = Ws[k4 * 4 + j][q];
                acc.x = fmaf(xs, wv.x, acc.x);
                acc.y = fmaf(xs, wv.y, acc.y);
                acc.z = fmaf(xs, wv.z, acc.z);
                acc.w = fmaf(xs, wv.w, acc.w);
            }
        }
        union { __half2 h[2]; float2 f; } u;
        u.h[0] = __floats2half2_rn(acc.x, acc.y);
        u.h[1] = __floats2half2_rn(acc.z, acc.w);
        int ch  = q >> 1;                     // channel chunk 0..7
        int off = (q & 1) * 4;                // half-chunk offset
        *(float2*)(Y + ((size_t)ch * N_NODES + rw) * 8 + off) = u.f;
    }
}

// ---------------------------------------------------------------------------
// 4) ell_fill: one 512-thread block per bucket; LDS cursors assign ELL slots;
//    LDS float atomics build weighted degree -> deg_arr + dis.
// ---------------------------------------------------------------------------
__global__ void ell_fill_kernel(const unsigned* __restrict__ scanned,
                                const unsigned* __restrict__ blockSums,
                                const unsigned long long* __restrict__ srt,
                                unsigned* __restrict__ ell,
                                unsigned* __restrict__ deg_arr, float* __restrict__ dis) {
    __shared__ unsigned cb[512];
    __shared__ unsigned cur[128];
    __shared__ float    wsum[128];
    int t = threadIdx.x;
    chunk_scan(blockSums, cb, t);
    if (t < 128) { cur[t] = 0; wsum[t] = 0.f; }
    __syncthreads();
    int b = blockIdx.x;
    size_t h0 = (size_t)b * NBLK;
    size_t h1 = (size_t)(b + 1) * NBLK;
    unsigned c0 = (unsigned)(h0 >> 10), c1 = (unsigned)(h1 >> 10);
    unsigned start = scanned[h0] + (c0 ? cb[c0 - 1] : 0u);
    unsigned end   = (b + 1 < NBUCK) ? (scanned[h1] + (c1 ? cb[c1 - 1] : 0u))
                                     : (unsigned)N_EDGES;
    for (unsigned i = start + t; i < end; i += 512) {
        unsigned long long v = srt[i];
        unsigned c   = (unsigned)(v >> 32);
        unsigned rec = (unsigned)v;
        unsigned cl  = c & 127u;
        unsigned k   = atomicAdd(&cur[cl], 1u);
        if (k < MAXDEG) ell[(size_t)c * MAXDEG + k] = rec;
        atomicAdd(&wsum[cl], (float)(rec & 32767u) * EW_INV);
    }
    __syncthreads();
    if (t < 128) {
        int c = b * 128 + t;
        if (c < N_NODES) {
            deg_arr[c] = min(cur[t], (unsigned)MAXDEG);
            dis[c]     = rsqrtf(wsum[t] + 1.0f);
        }
    }
}

// ---------------------------------------------------------------------------
// 5) dense GEMM, fp16 input: Yc[8][N][8] = fp16( Xh[N,64] @ W[64,64] ),
//    chunk-major output.
// ---------------------------------------------------------------------------
__global__ void gemm64h_f16_kernel(const __half* __restrict__ X, const float* __restrict__ W,
                                   __half* __restrict__ Y, int nrows) {
    __shared__ float4 Ws[64][16];
    int t = threadIdx.x;
    for (int i = t; i < 64 * 16; i += 256)
        ((float4*)Ws)[i] = ((const float4*)W)[i];
    __syncthreads();

    int q   = t & 15;
    int sub = t >> 4;
    int row = blockIdx.x * 16 + sub;
    if (row >= nrows) return;
    const float4* xr = (const float4*)(X + (size_t)row * 64);
    float4 acc = {0.f, 0.f, 0.f, 0.f};
#pragma unroll
    for (int k8 = 0; k8 < 8; ++k8) {
        float4 raw = xr[k8];
        const __half2* hp = (const __half2*)&raw;
#pragma unroll
        for (int j = 0; j < 4; ++j) {
            float xs0 = __low2float(hp[j]);
            float xs1 = __high2float(hp[j]);
            float4 w0 = Ws[k8 * 8 + 2 * j][q];
            float4 w1 = Ws[k8 * 8 + 2 * j + 1][q];
            acc.x = fmaf(xs0, w0.x, acc.x); acc.y = fmaf(xs0, w0.y, acc.y);
            acc.z = fmaf(xs0, w0.z, acc.z); acc.w = fmaf(xs0, w0.w, acc.w);
            acc.x = fmaf(xs1, w1.x, acc.x); acc.y = fmaf(xs1, w1.y, acc.y);
            acc.z = fmaf(xs1, w1.z, acc.z); acc.w = fmaf(xs1, w1.w, acc.w);
        }
    }
    union { __half2 h[2]; float2 f; } u;
    u.h[0] = __floats2half2_rn(acc.x, acc.y);
    u.h[1] = __floats2half2_rn(acc.z, acc.w);
    int ch  = q >> 1;
    int off = (q & 1) * 4;
    *(float2*)(Y + ((size_t)ch * N_NODES + row) * 8 + off) = u.f;
}

// edge loop body: accumulate one edge's 8 fp16 channels via 4 hfma2
__device__ inline void fma_pk(float4 raw, __half2 nv, __half2* acc) {
    const __half2* ha = (const __half2*)&raw;
    acc[0] = __hfma2(nv, ha[0], acc[0]);
    acc[1] = __hfma2(nv, ha[1], acc[1]);
    acc[2] = __hfma2(nv, ha[2], acc[2]);
    acc[3] = __hfma2(nv, ha[3], acc[3]);
}

// ---------------------------------------------------------------------------
// 6) gather_chunk: channel-chunked aggregate. Block handles chunk=bid%8 for
//    32 nodes; its random table reads hit a 1.6 MB chunk -> per-XCD L2
//    resident. lane = (node-sub 0..3) x (edge-slot 0..15); per-lane direct
//    rec -> {dis, tbl} chain (depth 2), fp16 accumulate, 4-level butterfly.
//    Epilogue writes the node's 8-channel H slice (relu(agg + dd*xself + b)).
// ---------------------------------------------------------------------------
__global__ void gather_chunk_kernel(const unsigned* __restrict__ deg_arr,
                                    const unsigned* __restrict__ ell,
                                    const __half* __restrict__ tbl,   // [8][N][8]
                                    const float* __restrict__ dis,
                                    const float* __restrict__ b,
                                    __half* __restrict__ H) {         // [N][64]
    int bid   = blockIdx.x;
    int chunk = bid & 7;
    int grp   = bid >> 3;
    int t     = threadIdx.x;
    int lane  = t & 63;
    int le    = lane & 15;                       // edge slot
    int node  = grp * NPB + (t >> 6) * 4 + (lane >> 4);
    int deg   = (int)deg_arr[node];
    float dc  = dis[node];
    const unsigned* erow  = ell + (size_t)node * MAXDEG;
    const __half*   tbase = tbl + (size_t)chunk * N_NODES * 8;

    __half2 acc[4] = {__float2half2_rn(0.f), __float2half2_rn(0.f),
                      __float2half2_rn(0.f), __float2half2_rn(0.f)};
    for (int s = le; s < deg; s += 16) {
        unsigned rec = erow[s];
        int   src = (int)(rec >> 15);
        float nv  = dis[src] * ((float)(rec & 32767u) * EW_INV) * dc;
        __half2 nvh = __float2half2_rn(nv);
        float4 raw = *(const float4*)(tbase + (size_t)src * 8);
        fma_pk(raw, nvh, acc);
    }
    // butterfly over the 16 edge slots (masks 1,2,4,8 stay in the group)
#pragma unroll
    for (int m = 1; m <= 8; m <<= 1) {
#pragma unroll
        for (int i = 0; i < 4; ++i) {
            int ai; __builtin_memcpy(&ai, &acc[i], 4);
            int bi = __shfl_xor(ai, m, 64);
            __half2 bh; __builtin_memcpy(&bh, &bi, 4);
            acc[i] = __hadd2(acc[i], bh);
        }
    }
    if (le == 0) {
        float dd = dc * dc;
        float4 xraw = *(const float4*)(tbase + (size_t)node * 8);
        const __half2* hp = (const __half2*)&xraw;
        float4 b0 = *(const float4*)(b + chunk * 8);
        float4 b1 = *(const float4*)(b + chunk * 8 + 4);
        float bb[8] = {b0.x, b0.y, b0.z, b0.w, b1.x, b1.y, b1.z, b1.w};
        float h[8];
#pragma unroll
        for (int i = 0; i < 4; ++i) {
            float a0 = __low2float(acc[i]),  a1 = __high2float(acc[i]);
            float x0 = __low2float(hp[i]),   x1 = __high2float(hp[i]);
            h[2 * i]     = fmaxf(fmaf(dd, x0, a0) + bb[2 * i], 0.f);
            h[2 * i + 1] = fmaxf(fmaf(dd, x1, a1) + bb[2 * i + 1], 0.f);
        }
        union { __half2 hh[4]; float4 f; } u;
        u.hh[0] = __floats2half2_rn(h[0], h[1]);
        u.hh[1] = __floats2half2_rn(h[2], h[3]);
        u.hh[2] = __floats2half2_rn(h[4], h[5]);
        u.hh[3] = __floats2half2_rn(h[6], h[7]);
        *(float4*)(H + (size_t)node * 64 + chunk * 8) = u.f;
    }
}

// ---------------------------------------------------------------------------
// 7) out_gemm: OUT[N,32] = tanh( H2[N,64] @ Wout + bout ), streaming dense.
// ---------------------------------------------------------------------------
__global__ void out_gemm_kernel(const __half* __restrict__ H2, const float* __restrict__ Wout,
                                const float* __restrict__ bout, float* __restrict__ OUT) {
    __shared__ float4 Ws4[64][8];   // Ws4[k][q] = Wout[k][4q..4q+3], 8 KB
    int t = threadIdx.x;
    for (int i = t; i < 512; i += 256)
        ((float4*)Ws4)[i] = ((const float4*)Wout)[i];
    __syncthreads();

    int q   = t & 7;                // 4 output channels
    int sub = t >> 3;               // 32 rows/block
    int rw  = blockIdx.x * 32 + sub;
    if (rw >= N_NODES) return;
    const float4* hr = (const float4*)(H2 + (size_t)rw * 64);   // 8 float4 = 64 halves
    float4 acc = *(const float4*)(bout + q * 4);
#pragma unroll
    for (int k8 = 0; k8 < 8; ++k8) {
        float4 raw = hr[k8];
        const __half2* hp = (const __half2*)&raw;
#pragma unroll
        for (int j = 0; j < 4; ++j) {
            float xs0 = __low2float(hp[j]);
            float xs1 = __high2float(hp[j]);
            float4 w0 = Ws4[k8 * 8 + 2 * j][q];
            float4 w1 = Ws4[k8 * 8 + 2 * j + 1][q];
            acc.x = fmaf(xs0, w0.x, acc.x); acc.y = fmaf(xs0, w0.y, acc.y);
            acc.z = fmaf(xs0, w0.z, acc.z); acc.w = fmaf(xs0, w0.w, acc.w);
            acc.x = fmaf(xs1, w1.x, acc.x); acc.y = fmaf(xs1, w1.y, acc.y);
            acc.z = fmaf(xs1, w1.z, acc.z); acc.w = fmaf(xs1, w1.w, acc.w);
        }
    }
    float4 v;
    v.x = 1.f - 2.f / (__expf(2.f * acc.x) + 1.f);
    v.y = 1.f - 2.f / (__expf(2.f * acc.y) + 1.f);
    v.z = 1.f - 2.f / (__expf(2.f * acc.z) + 1.f);
    v.w = 1.f - 2.f / (__expf(2.f * acc.w) + 1.f);
    *(float4*)(OUT + (size_t)rw * OUT_CH + q * 4) = v;
}

// ---------------------------------------------------------------------------
extern "C" void kernel_launch(void* const* d_in, const int* in_sizes, int n_in,
                              void* d_out, int out_size, void* d_ws, size_t ws_size,
                              hipStream_t stream) {
    const float* x     = (const float*)d_in[0];
    const int*   eidx  = (const int*)  d_in[1];
    const float* ew    = (const float*)d_in[2];
    const float* W1    = (const float*)d_in[3];
    const float* b1    = (const float*)d_in[4];
    const float* W2    = (const float*)d_in[5];
    const float* b2    = (const float*)d_in[6];
    const float* Wout  = (const float*)d_in[7];
    const float* bout  = (const float*)d_in[8];
    float*       out   = (float*)d_out;

    const int* row = eidx;             // edge_index[0]
    const int* col = eidx + N_EDGES;   // edge_index[1]

    // workspace layout (~49 MB)
    char*  ws   = (char*)d_ws;
    size_t offs = 0;
    auto alloc = [&](size_t bytes) {
        char* p = ws + offs;
        offs += (bytes + 1023) & ~(size_t)1023;
        return p;
    };
    unsigned* hist_g    = (unsigned*)alloc((size_t)HIST_TOT * sizeof(unsigned));
    unsigned* scanned   = (unsigned*)alloc((size_t)HIST_TOT * sizeof(unsigned));
    unsigned* blockSums = (unsigned*)alloc((size_t)NCHUNK * sizeof(unsigned));
    unsigned long long* srt = (unsigned long long*)alloc((size_t)N_EDGES * 8);
    unsigned* deg_arr   = (unsigned*)alloc((size_t)N_NODES * sizeof(unsigned));
    float*    dis       = (float*)   alloc((size_t)N_NODES * sizeof(float));
    unsigned* ell       = (unsigned*)alloc((size_t)N_NODES * MAXDEG * sizeof(unsigned));
    __half*   xwc       = (__half*)  alloc((size_t)NCH * N_NODES * 8 * sizeof(__half)); // chunked table
    __half*   hbuf      = (__half*)srt;   // srt dead after ell_fill; alias (12.8 MB fits)

    const int BLK  = 256;
    const int gGemm = (N_NODES + 15) / 16;             // 16 rows/block (gemm64h)

    // ---- preprocessing: counting-sort CSR/ELL build (no global atomics),
    //      with layer-1 GEMM (chunk-major out) fused into the scatter launch ----
    hist_kernel<<<NBLK, 1024, 0, stream>>>(col, hist_g);
    scan1_kernel<<<NCHUNK, 256, 0, stream>>>(hist_g, scanned, blockSums);
    scatter_gemm_kernel<<<NBLK + GEMMB, 1024, 0, stream>>>(row, col, ew, scanned,
                                                           blockSums, srt, x, W1, xwc);
    ell_fill_kernel<<<NBUCK_USED, 512, 0, stream>>>(scanned, blockSums, srt,
                                                    ell, deg_arr, dis);

    // ---- layer 1 aggregate + relu -> H [N][64] (fp16, aliased on srt) ----
    gather_chunk_kernel<<<GGATHER, 512, 0, stream>>>(deg_arr, ell, xwc, dis, b1, hbuf);

    // ---- layer 2: GEMM (H @ W2 -> chunked xwc reused), aggregate -> H2 ----
    gemm64h_f16_kernel<<<gGemm, BLK, 0, stream>>>(hbuf, W2, xwc, N_NODES);
    gather_chunk_kernel<<<GGATHER, 512, 0, stream>>>(deg_arr, ell, xwc, dis, b2, hbuf);

    // ---- output projection: tanh(H2 @ Wout + bout) ----
    out_gemm_kernel<<<GOUT, BLK, 0, stream>>>(hbuf, Wout, bout, out);
}

// Round 20
// 153.025 us; speedup vs baseline: 2.1185x; 2.1185x over previous
//
#include <hip/hip_runtime.h>
#include <hip/hip_fp16.h>
#include <math.h>

#define N_NODES 100000
#define N_EDGES 1600000
#define IN_CH   64
#define GCN_CH  64
#define OUT_CH  32
#define MAXDEG  48   // P(deg >= 48) ~ 1e-10/node under Binomial(1.6M, 1e-5); guarded

#define EW_SCALE  32768.0f              // 15-bit fixed point for ELL records
#define EW_INV    (1.0f / 32768.0f)

// counting-sort geometry
#define BSHIFT   7
#define NBUCK    1024                         // col>>7  (col < 2^17)
#define NBUCK_USED ((N_NODES + 127) / 128)    // 782 buckets actually populated
#define EPB      4096                         // edges per hist/scatter block
#define NBLK     ((N_EDGES + EPB - 1) / EPB)  // 391
#define HIST_TOT (NBUCK * NBLK)               // 400384 = 391 chunks of 1024 exactly
#define NCHUNK   (HIST_TOT / 1024)            // 391 (exact)
#define GEMMB    ((N_NODES + 63) / 64)        // 1563 gemm blocks (64 rows @ 1024 thr)

typedef _Float16 f16x2 __attribute__((ext_vector_type(2)));

__device__ inline float fdot2(__half2 a, __half2 b, float c) {
    f16x2 av, bv;
    __builtin_memcpy(&av, &a, 4);
    __builtin_memcpy(&bv, &b, 4);
    return __builtin_amdgcn_fdot2(av, bv, c, false);
}

// ---------------------------------------------------------------------------
// 1) hist: per-block LDS histogram over 1024 coarse buckets.
// ---------------------------------------------------------------------------
__global__ void hist_kernel(const int* __restrict__ col, unsigned* __restrict__ hist_g) {
    __shared__ unsigned sh[NBUCK];
    int blk = blockIdx.x;
    for (int i = threadIdx.x; i < NBUCK; i += 1024) sh[i] = 0;
    __syncthreads();
    int base = blk * EPB;
    int lim  = min(EPB, N_EDGES - base);
    for (int i = threadIdx.x; i < lim; i += 1024)
        atomicAdd(&sh[(unsigned)col[base + i] >> BSHIFT], 1u);
    __syncthreads();
    for (int b = threadIdx.x; b < NBUCK; b += 1024)
        hist_g[(size_t)b * NBLK + blk] = sh[b];
}

// ---------------------------------------------------------------------------
// 2) scan1: per-chunk exclusive scan; blockSums keeps RAW chunk totals
//    (consumers do the 391-entry top-level scan themselves in LDS).
// ---------------------------------------------------------------------------
__global__ void scan1_kernel(const unsigned* __restrict__ in, unsigned* __restrict__ outp,
                             unsigned* __restrict__ blockSums) {
    __shared__ unsigned sdata[256];
    int t = threadIdx.x;
    int base = blockIdx.x * 1024 + t * 4;
    unsigned v[4];
    unsigned sum = 0;
#pragma unroll
    for (int i = 0; i < 4; ++i) { v[i] = in[base + i]; sum += v[i]; }
    sdata[t] = sum;
    __syncthreads();
    for (int off = 1; off < 256; off <<= 1) {
        unsigned x = (t >= off) ? sdata[t - off] : 0;
        __syncthreads();
        sdata[t] += x;
        __syncthreads();
    }
    unsigned excl = sdata[t] - sum;
    if (t == 255) blockSums[blockIdx.x] = sdata[t];
    unsigned run = excl;
#pragma unroll
    for (int i = 0; i < 4; ++i) { outp[base + i] = run; run += v[i]; }
}

// helper: inclusive Hillis-Steele scan of raw chunk totals into cb[512]
// (threads >= 512 just hit the barriers).  chunk base = cb[chunk-1] (0 for 0).
__device__ inline void chunk_scan(const unsigned* __restrict__ bsum, unsigned* cb,
                                  int t) {
    if (t < 512) cb[t] = (t < NCHUNK) ? bsum[t] : 0u;
    __syncthreads();
    for (int off = 1; off < 512; off <<= 1) {
        unsigned x = 0;
        if (t < 512 && t >= off) x = cb[t - off];
        __syncthreads();
        if (t < 512) cb[t] += x;
        __syncthreads();
    }
}

// ---------------------------------------------------------------------------
// 3) scatter (+ fused layer-1 GEMM, block-role split).
//    scatter role: BLOCK-LOCAL COUNTING SORT into LDS, then bucket-run
//    coalesced global writes.  srt record: (col<<32)|(src<<15)|u15(ew)
//    gemm role: Yh[N,64] = fp16( X @ W1 ), 64 rows/block.
// ---------------------------------------------------------------------------
__global__ void scatter_gemm_kernel(const int* __restrict__ row, const int* __restrict__ col,
                                    const float* __restrict__ ew,
                                    const unsigned* __restrict__ scanned,
                                    const unsigned* __restrict__ blockSums,
                                    unsigned long long* __restrict__ srt,
                                    const float* __restrict__ X, const float* __restrict__ W,
                                    __half* __restrict__ Y) {
    __shared__ unsigned cb[512];                 // 2 KB  (chunk bases)
    __shared__ unsigned cur[NBUCK];              // 4 KB  (global bases)
    __shared__ unsigned lbase[NBUCK];            // 4 KB  (local exclusive bases)
    __shared__ unsigned lcur[NBUCK];             // 4 KB  (hist, then local cursors)
    __shared__ unsigned wsum[16];
    __shared__ unsigned long long lrec[EPB];     // 32 KB (locally sorted records)
    __shared__ float4   Ws[64][16];              // 4 KB  (gemm role)
    int t = threadIdx.x;
    int bid = blockIdx.x;

    if (bid < NBLK) {
        // ---- scatter role ----
        chunk_scan(blockSums, cb, t);
        lcur[t] = 0;
        __syncthreads();

        int blk  = bid;
        int base = blk * EPB;
        int lim  = min(EPB, N_EDGES - base);

        // pass 1: load records into registers, build local histogram
        unsigned long long recs[4];
        unsigned bks[4];
#pragma unroll
        for (int k = 0; k < 4; ++k) {
            int i = t + k * 1024;
            bool ok = i < lim;
            int e = base + (ok ? i : 0);
            unsigned c = (unsigned)col[e];
            unsigned r = (unsigned)row[e];
            float    w = ew[e];
            unsigned u15 = min((unsigned)(w * EW_SCALE + 0.5f), 32767u);
            recs[k] = ((unsigned long long)c << 32) | ((r << 15) | u15);
            bks[k]  = c >> BSHIFT;
            if (ok) atomicAdd(&lcur[bks[k]], 1u);
        }
        __syncthreads();

        // exclusive scan of local histogram (wave shfl + 16 wave-sums)
        {
            unsigned v = lcur[t];
            unsigned inc = v;
#pragma unroll
            for (int off = 1; off < 64; off <<= 1) {
                unsigned u = __shfl_up(inc, off, 64);
                if ((t & 63) >= off) inc += u;
            }
            if ((t & 63) == 63) wsum[t >> 6] = inc;
            __syncthreads();
            unsigned wprefix = 0;
            int wid = t >> 6;
            for (int wv = 0; wv < wid; ++wv) wprefix += wsum[wv];  // LDS broadcast
            lbase[t] = wprefix + inc - v;   // exclusive local base
            // global base for this (bucket, block)
            size_t hidx = (size_t)t * NBLK + blk;
            unsigned chunk = (unsigned)(hidx >> 10);
            cur[t]  = scanned[hidx] + (chunk ? cb[chunk - 1] : 0u);
            lcur[t] = lbase[t];             // re-purpose as local cursor
        }
        __syncthreads();

        // pass 2: place records into LDS, sorted by bucket
#pragma unroll
        for (int k = 0; k < 4; ++k) {
            int i = t + k * 1024;
            if (i < lim) {
                unsigned p = atomicAdd(&lcur[bks[k]], 1u);
                lrec[p] = recs[k];
            }
        }
        __syncthreads();

        // pass 3: bucket-run coalesced global writes
        for (int j = t; j < lim; j += 1024) {
            unsigned long long v = lrec[j];
            unsigned b = (unsigned)(v >> 32) >> BSHIFT;
            unsigned gpos = cur[b] + ((unsigned)j - lbase[b]);
            srt[gpos] = v;
        }
    } else {
        // ---- gemm role: 1024 threads, 64 rows/block ----
        ((float4*)Ws)[t] = ((const float4*)W)[t];   // exactly 1024 float4s
        __syncthreads();
        int gb  = bid - NBLK;
        int q   = t & 15;
        int sub = t >> 4;                           // 0..63
        int rw  = gb * 64 + sub;
        if (rw >= N_NODES) return;
        const float4* xr = (const float4*)(X + (size_t)rw * 64);
        float4 acc = {0.f, 0.f, 0.f, 0.f};
#pragma unroll
        for (int k4 = 0; k4 < 16; ++k4) {
            float4 xv = xr[k4];
#pragma unroll
            for (int j = 0; j < 4; ++j) {
                float xs = (j == 0) ? xv.x : (j == 1) ? xv.y : (j == 2) ? xv.z : xv.w;
                float4 wv = Ws[k4 * 4 + j][q];
                acc.x = fmaf(xs, wv.x, acc.x);
                acc.y = fmaf(xs, wv.y, acc.y);
                acc.z = fmaf(xs, wv.z, acc.z);
                acc.w = fmaf(xs, wv.w, acc.w);
            }
        }
        union { __half2 h[2]; float2 f; } u;
        u.h[0] = __floats2half2_rn(acc.x, acc.y);
        u.h[1] = __floats2half2_rn(acc.z, acc.w);
        *(float2*)(Y + (size_t)rw * 64 + q * 4) = u.f;
    }
}

// ---------------------------------------------------------------------------
// 4) ell_fill: one 512-thread block per bucket; LDS cursors assign ELL slots;
//    LDS float atomics build weighted degree -> deg_arr + dis.
// ---------------------------------------------------------------------------
__global__ void ell_fill_kernel(const unsigned* __restrict__ scanned,
                                const unsigned* __restrict__ blockSums,
                                const unsigned long long* __restrict__ srt,
                                unsigned* __restrict__ ell,
                                unsigned* __restrict__ deg_arr, float* __restrict__ dis) {
    __shared__ unsigned cb[512];
    __shared__ unsigned cur[128];
    __shared__ float    wsum[128];
    int t = threadIdx.x;
    chunk_scan(blockSums, cb, t);
    if (t < 128) { cur[t] = 0; wsum[t] = 0.f; }
    __syncthreads();
    int b = blockIdx.x;
    size_t h0 = (size_t)b * NBLK;
    size_t h1 = (size_t)(b + 1) * NBLK;
    unsigned c0 = (unsigned)(h0 >> 10), c1 = (unsigned)(h1 >> 10);
    unsigned start = scanned[h0] + (c0 ? cb[c0 - 1] : 0u);
    unsigned end   = (b + 1 < NBUCK) ? (scanned[h1] + (c1 ? cb[c1 - 1] : 0u))
                                     : (unsigned)N_EDGES;
    for (unsigned i = start + t; i < end; i += 512) {
        unsigned long long v = srt[i];
        unsigned c   = (unsigned)(v >> 32);
        unsigned rec = (unsigned)v;
        unsigned cl  = c & 127u;
        unsigned k   = atomicAdd(&cur[cl], 1u);
        if (k < MAXDEG) ell[(size_t)c * MAXDEG + k] = rec;
        atomicAdd(&wsum[cl], (float)(rec & 32767u) * EW_INV);
    }
    __syncthreads();
    if (t < 128) {
        int c = b * 128 + t;
        if (c < N_NODES) {
            deg_arr[c] = min(cur[t], (unsigned)MAXDEG);
            dis[c]     = rsqrtf(wsum[t] + 1.0f);
        }
    }
}

// ---------------------------------------------------------------------------
// 5) dense GEMM, fp16 input:  Yh[N,64] = fp16( Xh[N,64] @ W[64,64] )
// ---------------------------------------------------------------------------
__global__ void gemm64h_f16_kernel(const __half* __restrict__ X, const float* __restrict__ W,
                                   __half* __restrict__ Y, int nrows) {
    __shared__ float4 Ws[64][16];
    int t = threadIdx.x;
    for (int i = t; i < 64 * 16; i += 256)
        ((float4*)Ws)[i] = ((const float4*)W)[i];
    __syncthreads();

    int q   = t & 15;
    int sub = t >> 4;
    int row = blockIdx.x * 16 + sub;
    if (row >= nrows) return;
    const float4* xr = (const float4*)(X + (size_t)row * 64);  // 8 halves per float4
    float4 acc = {0.f, 0.f, 0.f, 0.f};
#pragma unroll
    for (int k8 = 0; k8 < 8; ++k8) {
        float4 raw = xr[k8];
        const __half2* hp = (const __half2*)&raw;
#pragma unroll
        for (int j = 0; j < 4; ++j) {
            float xs0 = __low2float(hp[j]);
            float xs1 = __high2float(hp[j]);
            float4 w0 = Ws[k8 * 8 + 2 * j][q];
            float4 w1 = Ws[k8 * 8 + 2 * j + 1][q];
            acc.x = fmaf(xs0, w0.x, acc.x); acc.y = fmaf(xs0, w0.y, acc.y);
            acc.z = fmaf(xs0, w0.z, acc.z); acc.w = fmaf(xs0, w0.w, acc.w);
            acc.x = fmaf(xs1, w1.x, acc.x); acc.y = fmaf(xs1, w1.y, acc.y);
            acc.z = fmaf(xs1, w1.z, acc.z); acc.w = fmaf(xs1, w1.w, acc.w);
        }
    }
    union { __half2 h[2]; float2 f; } u;
    u.h[0] = __floats2half2_rn(acc.x, acc.y);
    u.h[1] = __floats2half2_rn(acc.z, acc.w);
    *(float2*)(Y + (size_t)row * 64 + q * 4) = u.f;
}

// ---------------------------------------------------------------------------
// helper: epilogue — h[i] = relu(acc[i] + dd*xself[i] + b[i]),  dd = dis^2
// ---------------------------------------------------------------------------
__device__ inline void make_h_raw(const float* acc, float4 xraw,
                                  const float* b, int q, float dd, float* h) {
    const __half2* hp = (const __half2*)&xraw;
    float4 b0 = *(const float4*)(b + q * 8);
    float4 b1 = *(const float4*)(b + q * 8 + 4);
    float xs[8] = {__low2float(hp[0]), __high2float(hp[0]),
                   __low2float(hp[1]), __high2float(hp[1]),
                   __low2float(hp[2]), __high2float(hp[2]),
                   __low2float(hp[3]), __high2float(hp[3])};
    float bb[8] = {b0.x, b0.y, b0.z, b0.w, b1.x, b1.y, b1.z, b1.w};
#pragma unroll
    for (int i = 0; i < 8; ++i)
        h[i] = fmaxf(fmaf(dd, xs[i], acc[i]) + bb[i], 0.f);
}

// edge loop body: accumulate one edge's 8 fp16 channels via 4 hfma2
__device__ inline void fma_pk(float4 raw, __half2 nv, __half2* acc) {
    const __half2* ha = (const __half2*)&raw;
    acc[0] = __hfma2(nv, ha[0], acc[0]);
    acc[1] = __hfma2(nv, ha[1], acc[1]);
    acc[2] = __hfma2(nv, ha[2], acc[2]);
    acc[3] = __hfma2(nv, ha[3], acc[3]);
}

// ---------------------------------------------------------------------------
// shared aggregation core: TWO nodes per wave, edge loop UNROLLED 4x.
// lane = (half = lane>>5) x (edge-group g = (lane&31)>>3, 4 groups) x (oct q).
// Per iteration each lane issues FOUR independent 16 B gathers before
// consuming any.  Slots >= deg are zero-weight; phantom loads hit row 0.
// ---------------------------------------------------------------------------
__device__ inline void gather_core(int node, int lane,
                                   const unsigned* __restrict__ deg_arr,
                                   const unsigned* __restrict__ ell,
                                   const __half* __restrict__ XWh,
                                   const float* __restrict__ dis,
                                   float& dc_out, float4& xself, float* accf) {
    int half = lane >> 5;
    int l    = lane & 31;
    int g    = l >> 3;          // edge group 0..3
    int q    = l & 7;           // channel oct
    int base = half << 5;

    int deg = (int)deg_arr[node];
    const unsigned* erow = ell + (size_t)node * MAXDEG;
    unsigned rec1 = (l < deg) ? erow[l] : 0u;
    unsigned rec2 = (l < 16 && 32 + l < deg) ? erow[32 + l] : 0u;
    float dc = dis[node];
    dc_out = dc;

    int   src1 = (int)(rec1 >> 15);
    float nv1  = dis[src1] * ((float)(rec1 & 32767u) * EW_INV) * dc;
    int   src2 = (int)(rec2 >> 15);
    float nv2  = dis[src2] * ((float)(rec2 & 32767u) * EW_INV) * dc;
    __half2 t1 = __float2half2_rn(nv1), t2 = __float2half2_rn(nv2);
    int nv1pk, nv2pk;
    __builtin_memcpy(&nv1pk, &t1, 4);
    __builtin_memcpy(&nv2pk, &t2, 4);

    xself = *(const float4*)(XWh + (size_t)node * 64 + q * 8);

    int dmax = max(deg, __shfl_xor(deg, 32, 64));   // wave-uniform

    __half2 acc[4] = {__float2half2_rn(0.f), __float2half2_rn(0.f),
                      __float2half2_rn(0.f), __float2half2_rn(0.f)};
    int s1 = min(dmax, 32);
    for (int s = 0; s < s1; s += 16) {
        // stage four slots, issue all four loads before consuming any
        int srcA  = __shfl(src1,  base + s + g, 64);
        int nvA_i = __shfl(nv1pk, base + s + g, 64);
        int srcB  = __shfl(src1,  base + s + 4 + g, 64);
        int nvB_i = __shfl(nv1pk, base + s + 4 + g, 64);
        int srcC  = __shfl(src1,  base + s + 8 + g, 64);
        int nvC_i = __shfl(nv1pk, base + s + 8 + g, 64);
        int srcD  = __shfl(src1,  base + s + 12 + g, 64);  // <= base+31
        int nvD_i = __shfl(nv1pk, base + s + 12 + g, 64);
        float4 rawA = *(const float4*)(XWh + (size_t)srcA * 64 + q * 8);
        float4 rawB = *(const float4*)(XWh + (size_t)srcB * 64 + q * 8);
        float4 rawC = *(const float4*)(XWh + (size_t)srcC * 64 + q * 8);
        float4 rawD = *(const float4*)(XWh + (size_t)srcD * 64 + q * 8);
        __half2 nvA, nvB, nvC, nvD;
        __builtin_memcpy(&nvA, &nvA_i, 4);
        __builtin_memcpy(&nvB, &nvB_i, 4);
        __builtin_memcpy(&nvC, &nvC_i, 4);
        __builtin_memcpy(&nvD, &nvD_i, 4);
        fma_pk(rawA, nvA, acc);
        fma_pk(rawB, nvB, acc);
        fma_pk(rawC, nvC, acc);
        fma_pk(rawD, nvD, acc);
    }
    if (dmax > 32) {            // rare (~5 nodes globally)
        for (int s = 32; s < dmax; s += 4) {
            int srcB  = __shfl(src2,  base + (s - 32) + g, 64);
            int nvB_i = __shfl(nv2pk, base + (s - 32) + g, 64);
            float4 raw = *(const float4*)(XWh + (size_t)srcB * 64 + q * 8);
            __half2 nvB; __builtin_memcpy(&nvB, &nvB_i, 4);
            fma_pk(raw, nvB, acc);
        }
    }
    // fp16 butterfly over edge-groups (masks 8, 16 stay within the half)
#pragma unroll
    for (int m = 8; m <= 16; m <<= 1) {
#pragma unroll
        for (int i = 0; i < 4; ++i) {
            int ai; __builtin_memcpy(&ai, &acc[i], 4);
            int bi = __shfl_xor(ai, m, 64);
            __half2 bh; __builtin_memcpy(&bh, &bi, 4);
            acc[i] = __hadd2(acc[i], bh);
        }
    }
#pragma unroll
    for (int i = 0; i < 4; ++i) {
        accf[2 * i]     = __low2float(acc[i]);
        accf[2 * i + 1] = __high2float(acc[i]);
    }
}

// ---------------------------------------------------------------------------
// 6) gather_h: 2 nodes/wave -> H (fp16).  N_NODES % 16 == 0 (exact grid).
// ---------------------------------------------------------------------------
__global__ void gather_h_kernel(const unsigned* __restrict__ deg_arr,
                                const unsigned* __restrict__ ell,
                                const __half* __restrict__ XWh,
                                const float* __restrict__ dis, const float* __restrict__ b,
                                __half* __restrict__ H) {
    int lane = threadIdx.x & 63;
    int node = blockIdx.x * 16 + (threadIdx.x >> 6) * 2 + (lane >> 5);
    int l = lane & 31;
    int q = l & 7;

    float dc; float4 xself; float accf[8];
    gather_core(node, lane, deg_arr, ell, XWh, dis, dc, xself, accf);

    if ((l >> 3) == 0) {       // g==0 lanes of each half store
        float h[8];
        make_h_raw(accf, xself, b, q, dc * dc, h);
        union { __half2 hh[4]; float4 f; } u;
        u.hh[0] = __floats2half2_rn(h[0], h[1]);
        u.hh[1] = __floats2half2_rn(h[2], h[3]);
        u.hh[2] = __floats2half2_rn(h[4], h[5]);
        u.hh[3] = __floats2half2_rn(h[6], h[7]);
        *(float4*)(H + (size_t)node * 64 + q * 8) = u.f;
    }
}

// ---------------------------------------------------------------------------
// 7) gather_out: 2 nodes/wave; each half does its node's full 32-kpair
//    fdot2 matvec (no cross-half reduce), fast tanh, all 64 lanes store.
// ---------------------------------------------------------------------------
__global__ void gather_out_kernel(const unsigned* __restrict__ deg_arr,
                                  const unsigned* __restrict__ ell,
                                  const __half* __restrict__ XWh,
                                  const float* __restrict__ dis, const float* __restrict__ b,
                                  const float* __restrict__ Wout, const float* __restrict__ bout,
                                  float* __restrict__ OUT) {
    __shared__ __half2 Ws2[32][32];   // Ws2[kp][j] = (Wout[2kp][j], Wout[2kp+1][j])
    {
        for (int idx = threadIdx.x; idx < 32 * 32; idx += (int)blockDim.x) {
            int kp = idx >> 5, j = idx & 31;
            Ws2[kp][j] = __floats2half2_rn(Wout[(2 * kp) * OUT_CH + j],
                                           Wout[(2 * kp + 1) * OUT_CH + j]);
        }
        __syncthreads();
    }

    int lane = threadIdx.x & 63;
    int node = blockIdx.x * 16 + (threadIdx.x >> 6) * 2 + (lane >> 5);
    int half = lane >> 5;
    int l = lane & 31;
    int q = l & 7;
    int base = half << 5;

    float dc; float4 xself; float accf[8];
    gather_core(node, lane, deg_arr, ell, XWh, dis, dc, xself, accf);

    float h[8];
    make_h_raw(accf, xself, b, q, dc * dc, h);

    // pack h to 4 half2; matvec: out[l] = sum_kp dot2(h_kp, Wout_kp[l])
    int hpk[4];
#pragma unroll
    for (int i = 0; i < 4; ++i) {
        __half2 t2 = __floats2half2_rn(h[2 * i], h[2 * i + 1]);
        __builtin_memcpy(&hpk[i], &t2, 4);
    }
    float partial = 0.f;
#pragma unroll
    for (int kk = 0; kk < 32; ++kk) {
        int hv_i = __shfl(hpk[kk & 3], base + (kk >> 2), 64);
        __half2 hv; __builtin_memcpy(&hv, &hv_i, 4);
        partial = fdot2(hv, Ws2[kk][l], partial);
    }
    float v = partial + bout[l];
    float e = __expf(2.f * v);                 // tanh = 1 - 2/(e^{2v}+1)
    OUT[(size_t)node * OUT_CH + l] = 1.f - 2.f / (e + 1.f);
}

// ---------------------------------------------------------------------------
extern "C" void kernel_launch(void* const* d_in, const int* in_sizes, int n_in,
                              void* d_out, int out_size, void* d_ws, size_t ws_size,
                              hipStream_t stream) {
    const float* x     = (const float*)d_in[0];
    const int*   eidx  = (const int*)  d_in[1];
    const float* ew    = (const float*)d_in[2];
    const float* W1    = (const float*)d_in[3];
    const float* b1    = (const float*)d_in[4];
    const float* W2    = (const float*)d_in[5];
    const float* b2    = (const float*)d_in[6];
    const float* Wout  = (const float*)d_in[7];
    const float* bout  = (const float*)d_in[8];
    float*       out   = (float*)d_out;

    const int* row = eidx;             // edge_index[0]
    const int* col = eidx + N_EDGES;   // edge_index[1]

    // workspace layout (~49 MB)
    char*  ws   = (char*)d_ws;
    size_t offs = 0;
    auto alloc = [&](size_t bytes) {
        char* p = ws + offs;
        offs += (bytes + 1023) & ~(size_t)1023;
        return p;
    };
    unsigned* hist_g    = (unsigned*)alloc((size_t)HIST_TOT * sizeof(unsigned));
    unsigned* scanned   = (unsigned*)alloc((size_t)HIST_TOT * sizeof(unsigned));
    unsigned* blockSums = (unsigned*)alloc((size_t)NCHUNK * sizeof(unsigned));
    unsigned long long* srt = (unsigned long long*)alloc((size_t)N_EDGES * 8);
    unsigned* deg_arr   = (unsigned*)alloc((size_t)N_NODES * sizeof(unsigned));
    float*    dis       = (float*)   alloc((size_t)N_NODES * sizeof(float));
    unsigned* ell       = (unsigned*)alloc((size_t)N_NODES * MAXDEG * sizeof(unsigned));
    __half*   xwh       = (__half*)  alloc((size_t)N_NODES * GCN_CH * sizeof(__half));
    __half*   hbuf      = (__half*)srt;   // srt dead after ell_fill; alias (12.8 MB fits)

    const int BLK  = 256;
    const int BLKG = 512;                              // 8 waves = 16 nodes/block
    const int gGemm   = (N_NODES + 15) / 16;           // 16 rows/block (gemm64h)
    const int gGather = N_NODES / 16;                  // 6250 exact (100000 % 16 == 0)

    // ---- preprocessing: counting-sort CSR/ELL build (no global atomics),
    //      with layer-1 GEMM fused into the scatter launch ----
    hist_kernel<<<NBLK, 1024, 0, stream>>>(col, hist_g);
    scan1_kernel<<<NCHUNK, 256, 0, stream>>>(hist_g, scanned, blockSums);
    scatter_gemm_kernel<<<NBLK + GEMMB, 1024, 0, stream>>>(row, col, ew, scanned,
                                                           blockSums, srt, x, W1, xwh);
    ell_fill_kernel<<<NBUCK_USED, 512, 0, stream>>>(scanned, blockSums, srt,
                                                    ell, deg_arr, dis);

    // ---- layer 1 aggregate + relu -> H (fp16, aliased on srt) ----
    gather_h_kernel<<<gGather, BLKG, 0, stream>>>(deg_arr, ell, xwh, dis, b1, hbuf);

    // ---- layer 2: GEMM (H fp16 @ W2 -> xwh reused) + aggregate/out fused ----
    gemm64h_f16_kernel<<<gGemm, BLK, 0, stream>>>(hbuf, W2, xwh, N_NODES);
    gather_out_kernel<<<gGather, BLKG, 0, stream>>>(deg_arr, ell, xwh, dis, b2,
                                                    Wout, bout, out);
}